// Round 1
// baseline (138.497 us; speedup 1.0000x reference)
//
#include <hip/hip_runtime.h>

// N=512, D=512 pairwise scorer, all f32.
// left = E@W1[:D]; right = E@W1[D:]+b1; h = left[i]+right[j]; LN(D); GELU; @W2+b2; sigmoid.
// LN stats decompose: var = var_l[i]+var_r[j]+2*cov(i,j), cov = (1/D) lc@rc^T (centered).
// Never materialize [N,N,D]. Upper-triangle 16x16 pair tiles, mirrored store.

#define N_ 512
#define D_ 512

// ---------------- K1: left/right GEMMs ----------------
// 256 blocks = 32 rowgrps (16 rows) x 8 ccgrps (128 combined cols of 1024).
// 256 thr: t&31 -> col quad (128 cols), t>>5 -> row pair. 2 rows x 4 cols each:
// 32 FMA per (2 ds_read_b128 + 4 global dwordx4). W1 L2 traffic 64MB (~2us).
__global__ __launch_bounds__(256) void k_gemm(const float* __restrict__ E,
                                              const float* __restrict__ W1,
                                              const float* __restrict__ b1,
                                              float* __restrict__ W /* [1024][512] */) {
    __shared__ float e[16][516];  // 516 mod 32 = 4: 2-row stride -> 8 -> free 2-way
    const int t = threadIdx.x;
    const int cc = (blockIdx.x & 7) * 128;     // combined col base (0..896)
    const int r0 = (blockIdx.x >> 3) * 16;
    const int half = cc >> 9;
    const int c = (cc & 511) + (t & 31) * 4;
    const int rp = (t >> 5) * 2;

    for (int x = t; x < 16 * 128; x += 256) {
        int r = x >> 7, c4 = (x & 127) << 2;
        *(float4*)&e[r][c4] = *(const float4*)&E[(r0 + r) * D_ + c4];
    }
    __syncthreads();

    const float* __restrict__ wp = W1 + (half << 18) + c;
    float4 a0 = {0.f, 0.f, 0.f, 0.f}, a1 = {0.f, 0.f, 0.f, 0.f};
#pragma unroll 4
    for (int k = 0; k < D_; k += 4) {
        float4 e0 = *(float4*)&e[rp][k];
        float4 e1 = *(float4*)&e[rp + 1][k];
        float4 wa = *(const float4*)(wp + ((k + 0) << 9));
        float4 wb = *(const float4*)(wp + ((k + 1) << 9));
        float4 wc = *(const float4*)(wp + ((k + 2) << 9));
        float4 wd = *(const float4*)(wp + ((k + 3) << 9));
        a0.x = fmaf(e0.x, wa.x, a0.x); a0.y = fmaf(e0.x, wa.y, a0.y);
        a0.z = fmaf(e0.x, wa.z, a0.z); a0.w = fmaf(e0.x, wa.w, a0.w);
        a1.x = fmaf(e1.x, wa.x, a1.x); a1.y = fmaf(e1.x, wa.y, a1.y);
        a1.z = fmaf(e1.x, wa.z, a1.z); a1.w = fmaf(e1.x, wa.w, a1.w);
        a0.x = fmaf(e0.y, wb.x, a0.x); a0.y = fmaf(e0.y, wb.y, a0.y);
        a0.z = fmaf(e0.y, wb.z, a0.z); a0.w = fmaf(e0.y, wb.w, a0.w);
        a1.x = fmaf(e1.y, wb.x, a1.x); a1.y = fmaf(e1.y, wb.y, a1.y);
        a1.z = fmaf(e1.y, wb.z, a1.z); a1.w = fmaf(e1.y, wb.w, a1.w);
        a0.x = fmaf(e0.z, wc.x, a0.x); a0.y = fmaf(e0.z, wc.y, a0.y);
        a0.z = fmaf(e0.z, wc.z, a0.z); a0.w = fmaf(e0.z, wc.w, a0.w);
        a1.x = fmaf(e1.z, wc.x, a1.x); a1.y = fmaf(e1.z, wc.y, a1.y);
        a1.z = fmaf(e1.z, wc.z, a1.z); a1.w = fmaf(e1.z, wc.w, a1.w);
        a0.x = fmaf(e0.w, wd.x, a0.x); a0.y = fmaf(e0.w, wd.y, a0.y);
        a0.z = fmaf(e0.w, wd.z, a0.z); a0.w = fmaf(e0.w, wd.w, a0.w);
        a1.x = fmaf(e1.w, wd.x, a1.x); a1.y = fmaf(e1.w, wd.y, a1.y);
        a1.z = fmaf(e1.w, wd.z, a1.z); a1.w = fmaf(e1.w, wd.w, a1.w);
    }
    if (half) {
        float4 bb = *(const float4*)(b1 + c);
        a0.x += bb.x; a0.y += bb.y; a0.z += bb.z; a0.w += bb.w;
        a1.x += bb.x; a1.y += bb.y; a1.z += bb.z; a1.w += bb.w;
    }
    *(float4*)(W + ((half << 9) + r0 + rp) * D_ + c) = a0;
    *(float4*)(W + ((half << 9) + r0 + rp + 1) * D_ + c) = a1;
}

// ---------------- K2: center rows, per-row variance ----------------
// Wave-per-row: 256 blocks x 4 waves, shuffle-only reduce, zero barriers.
__global__ __launch_bounds__(256) void k_center(float* __restrict__ W,
                                                float* __restrict__ var) {
    const int t = threadIdx.x;
    const int lane = t & 63;
    const int r = (blockIdx.x << 2) + (t >> 6);
    float* p = W + r * D_;
    float4 v0 = *(float4*)&p[lane << 2];
    float4 v1 = *(float4*)&p[256 + (lane << 2)];
    float s = (v0.x + v0.y) + (v0.z + v0.w) + (v1.x + v1.y) + (v1.z + v1.w);
#pragma unroll
    for (int off = 32; off > 0; off >>= 1) s += __shfl_xor(s, off, 64);
    const float mean = s * (1.f / D_);
    v0.x -= mean; v0.y -= mean; v0.z -= mean; v0.w -= mean;
    v1.x -= mean; v1.y -= mean; v1.z -= mean; v1.w -= mean;
    float ss = v0.x * v0.x + v0.y * v0.y + v0.z * v0.z + v0.w * v0.w +
               v1.x * v1.x + v1.y * v1.y + v1.z * v1.z + v1.w * v1.w;
#pragma unroll
    for (int off = 32; off > 0; off >>= 1) ss += __shfl_xor(ss, off, 64);
    *(float4*)&p[lane << 2] = v0;
    *(float4*)&p[256 + (lane << 2)] = v1;
    if (lane == 0) var[r] = ss * (1.f / D_);
}

// ---------------- K3: fused cov -> rstd -> gelu-dot -> sigmoid ----------------
// 528 blocks = upper-triangle 16x16 pair tiles. 512 thr (8 waves) = 32 pair-
// threads (pt: 2x4 pair block, 8 chains) x 16 k-slices (ks, low 4 lane bits).
// Full 16x512 l/r tiles resident in LDS (66KB -> 2 blocks/CU, 16 waves/CU).
// ONE __syncthreads per block; k-slice reduction is a 4-step shfl_xor
// butterfly (no LDS reduce array -> no 16-way bank conflicts).
__device__ __forceinline__ void gelu_acc(float l, float r, float g, float be,
                                         float w, float rstd, float& acc) {
    // gelu_tanh(x) = x * sigmoid(1.5957691*(x + 0.044715 x^3))
    // q = log2(exp(-2y)) = x*(A*x^2+B), B = -2*log2e*0.79788456, A = B*0.044715
    float s = l + r;
    float x = fmaf(s * rstd, g, be);
    float x2 = x * x;
    float q = x * fmaf(-0.10294340f, x2, -2.30220935f);
    float eq = __builtin_amdgcn_exp2f(q);
    float ge = x * __builtin_amdgcn_rcpf(1.f + eq);
    acc = fmaf(ge, w, acc);
}

__global__ __launch_bounds__(512, 4) void k_pair(const float* __restrict__ W,
                                                 const float* __restrict__ var,
                                                 const float* __restrict__ gf,
                                                 const float* __restrict__ bef,
                                                 const float* __restrict__ wf,
                                                 const float* __restrict__ b2f,
                                                 float* __restrict__ out) {
    __shared__ float ls[16][516];   // 516 mod 32 = 4 -> reads spread 8 bank-quads
    __shared__ float rs[16][516];

    // decode upper-triangle tile index b -> (I, J), I<=J, 32 tile-rows
    const int b = blockIdx.x;
    int I = (int)((65.0f - sqrtf(4225.0f - 8.0f * (float)b)) * 0.5f);
    if (I < 0) I = 0;
    if (I > 31) I = 31;
#define S_(i) (32 * (i) - ((i) * ((i)-1)) / 2)
    while (S_(I) > b) --I;
    while (S_(I + 1) <= b) ++I;
    const int J = I + (b - S_(I));
#undef S_

    const int t = threadIdx.x;
    const int ks = t & 15;          // k-slice: lane bits 0..3 -> shfl-reducible
    const int pt = t >> 4;          // 0..31 pair-threads
    const int i2 = (pt & 7) * 2, j4 = (pt >> 3) * 4;
    const int Ibase = I * 16, Jbase = N_ + J * 16;

    // ---- stage full tiles once (4 iters, coalesced 1KB/row chunks) ----
    for (int x = t; x < 16 * 128; x += 512) {
        int r = x >> 7, c4 = (x & 127) << 2;
        *(float4*)&ls[r][c4] = *(const float4*)&W[(Ibase + r) * D_ + c4];
        *(float4*)&rs[r][c4] = *(const float4*)&W[(Jbase + r) * D_ + c4];
    }
    __syncthreads();   // the only barrier in this kernel

    // ---- pass A: cov (2x4 block, 8 chains) ----
    float cv[8];
#pragma unroll
    for (int c = 0; c < 8; ++c) cv[c] = 0.f;
#pragma unroll
    for (int it = 0; it < 8; ++it) {
        const int kq = (it * 16 + ks) * 4;
        float4 lq[2], rq[4];
#pragma unroll
        for (int d = 0; d < 2; ++d) lq[d] = *(float4*)&ls[i2 + d][kq];
#pragma unroll
        for (int d = 0; d < 4; ++d) rq[d] = *(float4*)&rs[j4 + d][kq];
#pragma unroll
        for (int di = 0; di < 2; ++di)
#pragma unroll
            for (int dj = 0; dj < 4; ++dj)
                cv[di * 4 + dj] += lq[di].x * rq[dj].x + lq[di].y * rq[dj].y +
                                   lq[di].z * rq[dj].z + lq[di].w * rq[dj].w;
    }
    // butterfly over the 16 k-slices: every lane ends with the full sum
#pragma unroll
    for (int c = 0; c < 8; ++c) {
        float v = cv[c];
        v += __shfl_xor(v, 1, 64);
        v += __shfl_xor(v, 2, 64);
        v += __shfl_xor(v, 4, 64);
        v += __shfl_xor(v, 8, 64);
        cv[c] = v;
    }

    // ---- rstd in-register (no LDS, no barrier) ----
    float rst[8];
    {
        float vl[2], vr[4];
#pragma unroll
        for (int d = 0; d < 2; ++d) vl[d] = var[Ibase + i2 + d];
#pragma unroll
        for (int d = 0; d < 4; ++d) vr[d] = var[Jbase - N_ + N_ + j4 + d];
#pragma unroll
        for (int di = 0; di < 2; ++di)
#pragma unroll
            for (int dj = 0; dj < 4; ++dj)
                rst[di * 4 + dj] =
                    rsqrtf(vl[di] + vr[dj] + cv[di * 4 + dj] * (2.f / D_) + 1e-5f);
    }

    // ---- pass B: gelu dot over the same resident tiles ----
    float ac[8];
#pragma unroll
    for (int c = 0; c < 8; ++c) ac[c] = 0.f;
#pragma unroll 2
    for (int it = 0; it < 8; ++it) {
        const int kq = (it * 16 + ks) * 4;
        float4 g4 = *(const float4*)&gf[kq];
        float4 be4 = *(const float4*)&bef[kq];
        float4 w4 = *(const float4*)&wf[kq];
        float4 lq[2], rq[4];
#pragma unroll
        for (int d = 0; d < 2; ++d) lq[d] = *(float4*)&ls[i2 + d][kq];
#pragma unroll
        for (int d = 0; d < 4; ++d) rq[d] = *(float4*)&rs[j4 + d][kq];
#pragma unroll
        for (int di = 0; di < 2; ++di)
#pragma unroll
            for (int dj = 0; dj < 4; ++dj) {
                float rr = rst[di * 4 + dj];
                float& a = ac[di * 4 + dj];
                gelu_acc(lq[di].x, rq[dj].x, g4.x, be4.x, w4.x, rr, a);
                gelu_acc(lq[di].y, rq[dj].y, g4.y, be4.y, w4.y, rr, a);
                gelu_acc(lq[di].z, rq[dj].z, g4.z, be4.z, w4.z, rr, a);
                gelu_acc(lq[di].w, rq[dj].w, g4.w, be4.w, w4.w, rr, a);
            }
    }
    // butterfly reduce z over k-slices
#pragma unroll
    for (int c = 0; c < 8; ++c) {
        float v = ac[c];
        v += __shfl_xor(v, 1, 64);
        v += __shfl_xor(v, 2, 64);
        v += __shfl_xor(v, 4, 64);
        v += __shfl_xor(v, 8, 64);
        ac[c] = v;
    }

    // ---- sigmoid + mirrored store (ks==0 lane of each pair-thread) ----
    if (ks == 0) {
        const float bb = b2f[0];
        float z[8];
#pragma unroll
        for (int c = 0; c < 8; ++c) {
            float zz = ac[c] + bb;
            z[c] = __builtin_amdgcn_rcpf(
                1.f + __builtin_amdgcn_exp2f(-1.44269504f * zz));
        }
        const int gi0 = Ibase + i2;
        const int gj0 = (Jbase - N_) + j4;
        if (I < J) {
            float4 o0 = {z[0], z[1], z[2], z[3]};
            float4 o1 = {z[4], z[5], z[6], z[7]};
            *(float4*)&out[gi0 * N_ + gj0] = o0;
            *(float4*)&out[(gi0 + 1) * N_ + gj0] = o1;
#pragma unroll
            for (int dj = 0; dj < 4; ++dj) {
                out[(gj0 + dj) * N_ + gi0] = z[dj];
                out[(gj0 + dj) * N_ + gi0 + 1] = z[4 + dj];
            }
        } else {  // diagonal tile: only pairs gi<=gj are valid
#pragma unroll
            for (int di = 0; di < 2; ++di)
#pragma unroll
                for (int dj = 0; dj < 4; ++dj) {
                    int gi = gi0 + di, gj = gj0 + dj;
                    if (gi <= gj) {
                        float zz = z[di * 4 + dj];
                        out[gi * N_ + gj] = zz;
                        out[gj * N_ + gi] = zz;
                    }
                }
        }
    }
}

extern "C" void kernel_launch(void* const* d_in, const int* in_sizes, int n_in,
                              void* d_out, int out_size, void* d_ws, size_t ws_size,
                              hipStream_t stream) {
    const float* E     = (const float*)d_in[0];
    const float* W1    = (const float*)d_in[1];
    const float* b1    = (const float*)d_in[2];
    const float* gamma = (const float*)d_in[3];
    const float* beta  = (const float*)d_in[4];
    const float* w2    = (const float*)d_in[5];
    const float* b2    = (const float*)d_in[6];
    float* out = (float*)d_out;

    float* F    = (float*)d_ws;
    float* lcrc = F;                  // [1024][512]: rows 0..511 lc, 512..1023 rc(+b1)
    float* var  = F + 1024 * 512;     // [1024]

    k_gemm<<<256, 256, 0, stream>>>(E, W1, b1, lcrc);
    k_center<<<256, 256, 0, stream>>>(lcrc, var);
    k_pair<<<528, 512, 0, stream>>>(lcrc, var, gamma, beta, w2, b2, out);
}